// Round 18
// baseline (69.376 us; speedup 1.0000x reference)
//
#include <hip/hip_runtime.h>

// x (4, 4096, 2048) f32; A,B,C,D (2048,) f32.  Single-kernel block-owned scan,
// direct-register form (R16 structure): each block owns (b, 8 f4-channels,
// ALL T); 8 same-sub lanes cover ch0..7 of one row = 128 B contiguous, so
// direct global loads/stores are coalescing-optimal; LDS holds only the
// prefix-exchange arrays. R18: THREADS 512->1024 (16 waves/block, 1 block/CU)
// doubles waves/SIMD 2->4 for latency hiding; per-thread geometry (TSUB=8,
// VGPR ~85) unchanged from the best R16 config.
#define BATCHN  4
#define TLEN    4096
#define D4      512       // DMODEL/4 in f4 units
#define DG      8         // f4 channels per block
#define NDG     64        // D4/DG
#define THREADS 1024
#define NSUB    128       // THREADS/DG  (t-subchunks per tile)
#define TSUB    8         // rows per thread per tile
#define TTILE   (NSUB * TSUB)   // 1024 rows per tile
#define NTILE   (TLEN / TTILE)  // 4

typedef float f4 __attribute__((ext_vector_type(4)));

// Saturating clamp to +-1e30 (survives fast-math; scrubs inf; identity for
// healthy channels). Proven R4-R17. Every composition is clamped, so no inf
// is ever stored -> no 0*inf -> no nan anywhere.
__device__ __forceinline__ float fin(float v) {
    return fminf(fmaxf(v, -1.0e30f), 1.0e30f);
}
__device__ __forceinline__ f4 fin4(f4 v) {
    f4 r;
    r.x = fin(v.x); r.y = fin(v.y); r.z = fin(v.z); r.w = fin(v.w);
    return r;
}

// Affine map h -> p*h + v ; composition later(earlier(h)).
struct pr { f4 p, v; };
__device__ __forceinline__ pr comp(pr later, pr earlier) {
    pr r;
    r.p = fin4(later.p * earlier.p);
    r.v = fin4(later.p * earlier.v + later.v);
    return r;
}
__device__ __forceinline__ f4 shflup4(f4 x, int delta) {
    f4 r;
    r.x = __shfl_up(x.x, (unsigned)delta, 64);
    r.y = __shfl_up(x.y, (unsigned)delta, 64);
    r.z = __shfl_up(x.z, (unsigned)delta, 64);
    r.w = __shfl_up(x.w, (unsigned)delta, 64);
    return r;
}

// Raw barrier: lgkmcnt(0) for LDS visibility, NO vmcnt drain (keeps the
// xnext prefetch loads and y stores in flight across phases).
#define BAR() do { asm volatile("s_waitcnt lgkmcnt(0)" ::: "memory"); \
                   __builtin_amdgcn_s_barrier();                       \
                   asm volatile("" ::: "memory"); } while (0)

__global__ __launch_bounds__(THREADS) void ssm_direct(
    const float* __restrict__ xg, const float* __restrict__ A,
    const float* __restrict__ B, const float* __restrict__ Cv,
    const float* __restrict__ Dv, float* __restrict__ yg) {
    // Double-buffered (by t&1) prefix-exchange arrays; ~8.5 KB total.
    __shared__ f4 wpP[2][NSUB], wpV[2][NSUB];
    __shared__ f4 totP[2][DG], totV[2][DG];

    const int tid  = threadIdx.x;
    const int lane = tid & 63;
    const int wid  = tid >> 6;        // wave 0..15
    const int dg   = blockIdx.x & (NDG - 1);
    const int b    = blockIdx.x >> 6;
    const int ch   = tid & (DG - 1);  // my f4 channel within the group
    const int sub  = tid >> 3;        // my t-subchunk (0..127)
    const int siw  = (lane >> 3);     // sub index within my wave (0..7)

    const int d4 = dg * DG + ch;
    const f4 a  = ((const f4*)A)[d4];
    const f4 bb = ((const f4*)B)[d4];
    const f4 cc = ((const f4*)Cv)[d4];
    const f4 dd = ((const f4*)Dv)[d4];
    const f4 a2 = fin4(a * a), a4 = fin4(a2 * a2), a8 = fin4(a4 * a4);
    const f4 ONE = {1.f, 1.f, 1.f, 1.f};
    const f4 ZERO = {0.f, 0.f, 0.f, 0.f};

    f4 S = ZERO;  // tile-running state, maintained redundantly in ALL threads

    // My row pointer: row (t*TTILE + sub*TSUB + i), channel ch.
    const size_t slice = (size_t)b * TLEN * D4 + (size_t)dg * DG + ch;
    const f4* xp = (const f4*)xg + slice + (size_t)sub * TSUB * D4;
    f4* yp = (f4*)yg + slice + (size_t)sub * TSUB * D4;

    // ---- Prologue: load tile 0 directly into registers. ----
    f4 xcur[TSUB], xnext[TSUB];
#pragma unroll
    for (int i = 0; i < TSUB; ++i) xcur[i] = xp[(size_t)i * D4];

    for (int t = 0; t < NTILE; ++t) {
        const int pb = t & 1;

        // (A) issue next tile's loads NOW; consumed at the rotate below.
        if (t + 1 < NTILE) {
            const f4* xn = xp + (size_t)(t + 1) * TTILE * D4;
#pragma unroll
            for (int i = 0; i < TSUB; ++i) xnext[i] = xn[(size_t)i * D4];
        }

        // (B) local scan of my 8 rows -> my subchunk's affine map (a8, v).
        pr me;
        {
            f4 v = ZERO;
#pragma unroll
            for (int i = 0; i < TSUB; ++i) v = fin4(a * v + bb * xcur[i]);
            me.p = a8; me.v = v;
        }

        // (B2) in-wave Kogge-Stone inclusive scan over the 8 subs (shuffles).
#pragma unroll
        for (int d = 1; d <= 4; d <<= 1) {
            pr up;
            up.p = shflup4(me.p, 8 * d);
            up.v = shflup4(me.v, 8 * d);
            if (siw >= d) me = comp(me, up);
        }
        if (siw == 7) { wpP[pb][wid * DG + ch] = me.p; wpV[pb][wid * DG + ch] = me.v; }
        BAR();

        // (B3) wave 0 scans the 16 wave-partials per channel via pair-compose:
        // lane (siw, c2) owns partials (2*siw, 2*siw+1) of channel c2.
        if (tid < 64) {
            const int c2 = tid & 7;
            pr p0; p0.p = wpP[pb][(2 * siw + 0) * DG + c2];
                   p0.v = wpV[pb][(2 * siw + 0) * DG + c2];
            pr p1; p1.p = wpP[pb][(2 * siw + 1) * DG + c2];
                   p1.v = wpV[pb][(2 * siw + 1) * DG + c2];
            pr q = comp(p1, p0);   // pair-composed map
#pragma unroll
            for (int d = 1; d <= 4; d <<= 1) {
                pr up;
                up.p = shflup4(q.p, 8 * d);
                up.v = shflup4(q.v, 8 * d);
                if (siw >= d) q = comp(q, up);
            }
            if (siw == 7) { totP[pb][c2] = q.p; totV[pb][c2] = q.v; }
            pr ex;                 // exclusive prefix of my pair-group
            ex.p = shflup4(q.p, 8);
            ex.v = shflup4(q.v, 8);
            if (siw == 0) { ex.p = ONE; ex.v = ZERO; }
            // split back: part 2*siw gets ex; part 2*siw+1 gets p0 ∘ ex.
            pr odd = comp(p0, ex);
            wpP[pb][(2 * siw + 0) * DG + c2] = ex.p;
            wpV[pb][(2 * siw + 0) * DG + c2] = ex.v;
            wpP[pb][(2 * siw + 1) * DG + c2] = odd.p;
            wpV[pb][(2 * siw + 1) * DG + c2] = odd.v;
        }
        BAR();

        // (B4) my exclusive start state = (within-wave excl) ∘ (wave excl),
        // applied to the running state S.
        pr wex; wex.p = wpP[pb][wid * DG + ch]; wex.v = wpV[pb][wid * DG + ch];
        pr mex;
        mex.p = shflup4(me.p, 8);
        mex.v = shflup4(me.v, 8);
        if (siw == 0) { mex.p = ONE; mex.v = ZERO; }
        pr st = comp(mex, wex);
        f4 s = fin4(fin4(st.p * S) + st.v);

        // advance S by the tile total (all threads, consistent per channel).
        S = fin4(fin4(totP[pb][ch] * S) + totV[pb][ch]);

        // (E) rescan my rows from s; store y DIRECTLY from registers
        // (8 same-sub lanes x 16B = 128B contiguous per row), non-temporal.
        f4* yt = yp + (size_t)t * TTILE * D4;
#pragma unroll
        for (int i = 0; i < TSUB; ++i) {
            f4 xi = xcur[i];
            s = fin4(a * s + bb * xi);
            f4 yv = fin4(cc * s + dd * xi);
            __builtin_nontemporal_store(yv, yt + (size_t)i * D4);
        }

        // rotate prefetched tile into xcur (reg-reg; compiler places the
        // precise vmcnt wait for xnext here).
        if (t + 1 < NTILE) {
#pragma unroll
            for (int i = 0; i < TSUB; ++i) xcur[i] = xnext[i];
        }
    }
}

extern "C" void kernel_launch(void* const* d_in, const int* in_sizes, int n_in,
                              void* d_out, int out_size, void* d_ws, size_t ws_size,
                              hipStream_t stream) {
    const float* x  = (const float*)d_in[0];
    const float* A  = (const float*)d_in[1];
    const float* B  = (const float*)d_in[2];
    const float* Cv = (const float*)d_in[3];
    const float* Dv = (const float*)d_in[4];
    float* y = (float*)d_out;

    const int nblocks = BATCHN * NDG;  // 256 blocks x 1024 threads
    ssm_direct<<<nblocks, THREADS, 0, stream>>>(x, A, B, Cv, Dv, y);
}

// Round 19
// 66.486 us; speedup vs baseline: 1.0435x; 1.0435x over previous
//
#include <hip/hip_runtime.h>

// x (4, 4096, 2048) f32; A,B,C,D (2048,) f32.  Single-kernel block-owned scan,
// direct-register form. R19: DG 8->4 gives 512 blocks (2/CU) x 8 waves =
// 4 waves/SIMD (VGPR ~84 <= 128 admits 16 waves/CU) -- the occupancy test
// R18 fumbled via spills (1024-thread bound forced VGPR 64, +90 MB scratch
// traffic). Per-thread geometry (TSUB=8, 512 threads) stays the proven
// spill-free R16 config. 4 same-sub lanes = 64 B contiguous = one DRAM burst.
#define BATCHN  4
#define TLEN    4096
#define D4      512       // DMODEL/4 in f4 units
#define DG      4         // f4 channels per block
#define NDG     128       // D4/DG
#define THREADS 512
#define NSUB    128       // THREADS/DG  (t-subchunks per tile)
#define TSUB    8         // rows per thread per tile
#define TTILE   (NSUB * TSUB)   // 1024 rows per tile
#define NTILE   (TLEN / TTILE)  // 4

typedef float f4 __attribute__((ext_vector_type(4)));

// Saturating clamp to +-1e30 (survives fast-math; scrubs inf; identity for
// healthy channels). Proven R4-R18. Every composition is clamped, so no inf
// is ever stored -> no 0*inf -> no nan anywhere.
__device__ __forceinline__ float fin(float v) {
    return fminf(fmaxf(v, -1.0e30f), 1.0e30f);
}
__device__ __forceinline__ f4 fin4(f4 v) {
    f4 r;
    r.x = fin(v.x); r.y = fin(v.y); r.z = fin(v.z); r.w = fin(v.w);
    return r;
}

// Affine map h -> p*h + v ; composition later(earlier(h)).
struct pr { f4 p, v; };
__device__ __forceinline__ pr comp(pr later, pr earlier) {
    pr r;
    r.p = fin4(later.p * earlier.p);
    r.v = fin4(later.p * earlier.v + later.v);
    return r;
}
__device__ __forceinline__ f4 shflup4(f4 x, int delta) {
    f4 r;
    r.x = __shfl_up(x.x, (unsigned)delta, 64);
    r.y = __shfl_up(x.y, (unsigned)delta, 64);
    r.z = __shfl_up(x.z, (unsigned)delta, 64);
    r.w = __shfl_up(x.w, (unsigned)delta, 64);
    return r;
}

// Raw barrier: lgkmcnt(0) for LDS visibility, NO vmcnt drain (keeps the
// xnext prefetch loads and y stores in flight across phases).
#define BAR() do { asm volatile("s_waitcnt lgkmcnt(0)" ::: "memory"); \
                   __builtin_amdgcn_s_barrier();                       \
                   asm volatile("" ::: "memory"); } while (0)

__global__ __launch_bounds__(THREADS) void ssm_direct(
    const float* __restrict__ xg, const float* __restrict__ A,
    const float* __restrict__ B, const float* __restrict__ Cv,
    const float* __restrict__ Dv, float* __restrict__ yg) {
    // Double-buffered (by t&1) prefix-exchange arrays; ~8.5 KB total.
    __shared__ f4 wpP[2][NSUB], wpV[2][NSUB];   // NSUB entries = 8 waves x 16 subs... indexed wave-major below
    __shared__ f4 totP[2][DG], totV[2][DG];

    const int tid  = threadIdx.x;
    const int lane = tid & 63;
    const int wid  = tid >> 6;        // wave 0..7
    const int dg   = blockIdx.x & (NDG - 1);
    const int b    = blockIdx.x >> 7; // log2(NDG)
    const int ch   = tid & (DG - 1);  // my f4 channel within the group (0..3)
    const int sub  = tid >> 2;        // my t-subchunk (0..127)
    const int siw  = (lane >> 2);     // sub index within my wave (0..15)

    const int d4 = dg * DG + ch;
    const f4 a  = ((const f4*)A)[d4];
    const f4 bb = ((const f4*)B)[d4];
    const f4 cc = ((const f4*)Cv)[d4];
    const f4 dd = ((const f4*)Dv)[d4];
    const f4 a2 = fin4(a * a), a4 = fin4(a2 * a2), a8 = fin4(a4 * a4);
    const f4 ONE = {1.f, 1.f, 1.f, 1.f};
    const f4 ZERO = {0.f, 0.f, 0.f, 0.f};

    f4 S = ZERO;  // tile-running state, maintained redundantly in ALL threads

    // My row pointer: row (t*TTILE + sub*TSUB + i), channel ch.
    const size_t slice = (size_t)b * TLEN * D4 + (size_t)dg * DG + ch;
    const f4* xp = (const f4*)xg + slice + (size_t)sub * TSUB * D4;
    f4* yp = (f4*)yg + slice + (size_t)sub * TSUB * D4;

    // ---- Prologue: load tile 0 directly into registers. ----
    f4 xcur[TSUB], xnext[TSUB];
#pragma unroll
    for (int i = 0; i < TSUB; ++i) xcur[i] = xp[(size_t)i * D4];

    for (int t = 0; t < NTILE; ++t) {
        const int pb = t & 1;

        // (A) issue next tile's loads NOW; consumed at the rotate below.
        if (t + 1 < NTILE) {
            const f4* xn = xp + (size_t)(t + 1) * TTILE * D4;
#pragma unroll
            for (int i = 0; i < TSUB; ++i) xnext[i] = xn[(size_t)i * D4];
        }

        // (B) local scan of my 8 rows -> my subchunk's affine map (a8, v).
        pr me;
        {
            f4 v = ZERO;
#pragma unroll
            for (int i = 0; i < TSUB; ++i) v = fin4(a * v + bb * xcur[i]);
            me.p = a8; me.v = v;
        }

        // (B2) in-wave Kogge-Stone inclusive scan over the 16 subs/wave.
#pragma unroll
        for (int d = 1; d <= 8; d <<= 1) {
            pr up;
            up.p = shflup4(me.p, 4 * d);
            up.v = shflup4(me.v, 4 * d);
            if (siw >= d) me = comp(me, up);
        }
        if (siw == 15) { wpP[pb][wid * DG + ch] = me.p; wpV[pb][wid * DG + ch] = me.v; }
        BAR();

        // (B3) wave 0 (32 active lanes) scans the 8 wave-partials per channel.
        if (tid < 32) {
            const int ww = tid >> 2, c2 = tid & 3;  // ww = siw here
            pr q; q.p = wpP[pb][tid]; q.v = wpV[pb][tid];
#pragma unroll
            for (int d = 1; d <= 4; d <<= 1) {
                pr up;
                up.p = shflup4(q.p, 4 * d);
                up.v = shflup4(q.v, 4 * d);
                if (ww >= d) q = comp(q, up);
            }
            if (ww == 7) { totP[pb][c2] = q.p; totV[pb][c2] = q.v; }
            pr ex;
            ex.p = shflup4(q.p, 4);
            ex.v = shflup4(q.v, 4);
            if (ww == 0) { ex.p = ONE; ex.v = ZERO; }
            wpP[pb][tid] = ex.p; wpV[pb][tid] = ex.v;
        }
        BAR();

        // (B4) my exclusive start state = (within-wave excl) ∘ (wave excl),
        // applied to the running state S.
        pr wex; wex.p = wpP[pb][wid * DG + ch]; wex.v = wpV[pb][wid * DG + ch];
        pr mex;
        mex.p = shflup4(me.p, 4);
        mex.v = shflup4(me.v, 4);
        if (siw == 0) { mex.p = ONE; mex.v = ZERO; }
        pr st = comp(mex, wex);
        f4 s = fin4(fin4(st.p * S) + st.v);

        // advance S by the tile total (all threads, consistent per channel).
        S = fin4(fin4(totP[pb][ch] * S) + totV[pb][ch]);

        // (E) rescan my rows from s; store y DIRECTLY from registers
        // (4 same-sub lanes x 16B = 64B contiguous per row), non-temporal.
        f4* yt = yp + (size_t)t * TTILE * D4;
#pragma unroll
        for (int i = 0; i < TSUB; ++i) {
            f4 xi = xcur[i];
            s = fin4(a * s + bb * xi);
            f4 yv = fin4(cc * s + dd * xi);
            __builtin_nontemporal_store(yv, yt + (size_t)i * D4);
        }

        // rotate prefetched tile into xcur (reg-reg; compiler places the
        // precise vmcnt wait for xnext here).
        if (t + 1 < NTILE) {
#pragma unroll
            for (int i = 0; i < TSUB; ++i) xcur[i] = xnext[i];
        }
    }
}

extern "C" void kernel_launch(void* const* d_in, const int* in_sizes, int n_in,
                              void* d_out, int out_size, void* d_ws, size_t ws_size,
                              hipStream_t stream) {
    const float* x  = (const float*)d_in[0];
    const float* A  = (const float*)d_in[1];
    const float* B  = (const float*)d_in[2];
    const float* Cv = (const float*)d_in[3];
    const float* Dv = (const float*)d_in[4];
    float* y = (float*)d_out;

    const int nblocks = BATCHN * NDG;  // 512 blocks x 512 threads = 2 blocks/CU
    ssm_direct<<<nblocks, THREADS, 0, stream>>>(x, A, B, Cv, Dv, y);
}

// Round 20
// 45.866 us; speedup vs baseline: 1.5126x; 1.4496x over previous
//
#include <hip/hip_runtime.h>

// x (4, 4096, 2048) f32; A,B,C,D (2048,) f32.  Single-kernel block-owned scan,
// direct-register form — EXACT revert to the best config (R16, 45.7 us).
// Each block owns (batch b, 8 f4-channels, ALL T). 8 same-sub lanes cover
// ch0..7 of one row = 128 B contiguous = one HBM granule -> direct global
// loads/stores are coalescing-optimal; LDS holds only the 4.5 KB
// prefix-exchange arrays. Measured at 96% of the per-CU VMEM-pipe ceiling
// (268 MB moved / 256 CU / 45.7 us = 9.6 B/cyc/CU vs ~10 measured max):
// TSUB=16 (R17), 1024 threads (R18, spilled), DG=4 (R19, 64B bursts +
// L3-residency loss) all regressed -- this geometry is the optimum.
#define BATCHN  4
#define TLEN    4096
#define D4      512       // DMODEL/4 in f4 units
#define DG      8         // f4 channels per block
#define NDG     64        // D4/DG
#define THREADS 512
#define NSUB    64        // THREADS/DG  (t-subchunks per tile)
#define TSUB    8         // rows per thread per tile
#define TTILE   (NSUB * TSUB)   // 512 rows per tile
#define NTILE   (TLEN / TTILE)  // 8

typedef float f4 __attribute__((ext_vector_type(4)));

// Saturating clamp to +-1e30 (survives fast-math; scrubs inf; identity for
// healthy channels). Proven R4-R19. Every composition is clamped, so no inf
// is ever stored -> no 0*inf -> no nan anywhere.
__device__ __forceinline__ float fin(float v) {
    return fminf(fmaxf(v, -1.0e30f), 1.0e30f);
}
__device__ __forceinline__ f4 fin4(f4 v) {
    f4 r;
    r.x = fin(v.x); r.y = fin(v.y); r.z = fin(v.z); r.w = fin(v.w);
    return r;
}

// Affine map h -> p*h + v ; composition later(earlier(h)).
struct pr { f4 p, v; };
__device__ __forceinline__ pr comp(pr later, pr earlier) {
    pr r;
    r.p = fin4(later.p * earlier.p);
    r.v = fin4(later.p * earlier.v + later.v);
    return r;
}
__device__ __forceinline__ f4 shflup4(f4 x, int delta) {
    f4 r;
    r.x = __shfl_up(x.x, (unsigned)delta, 64);
    r.y = __shfl_up(x.y, (unsigned)delta, 64);
    r.z = __shfl_up(x.z, (unsigned)delta, 64);
    r.w = __shfl_up(x.w, (unsigned)delta, 64);
    return r;
}

// Raw barrier: lgkmcnt(0) for LDS visibility, NO vmcnt drain (keeps the
// xnext prefetch loads and y stores in flight across phases).
#define BAR() do { asm volatile("s_waitcnt lgkmcnt(0)" ::: "memory"); \
                   __builtin_amdgcn_s_barrier();                       \
                   asm volatile("" ::: "memory"); } while (0)

__global__ __launch_bounds__(THREADS) void ssm_direct(
    const float* __restrict__ xg, const float* __restrict__ A,
    const float* __restrict__ B, const float* __restrict__ Cv,
    const float* __restrict__ Dv, float* __restrict__ yg) {
    // Double-buffered (by t&1) prefix-exchange arrays; ~4.5 KB total.
    __shared__ f4 wpP[2][NSUB], wpV[2][NSUB];
    __shared__ f4 totP[2][DG], totV[2][DG];

    const int tid  = threadIdx.x;
    const int lane = tid & 63;
    const int wid  = tid >> 6;        // wave 0..7
    const int dg   = blockIdx.x & (NDG - 1);
    const int b    = blockIdx.x >> 6;
    const int ch   = tid & (DG - 1);  // my f4 channel within the group
    const int sub  = tid >> 3;        // my t-subchunk (0..63)
    const int siw  = (lane >> 3);     // sub index within my wave (0..7)

    const int d4 = dg * DG + ch;
    const f4 a  = ((const f4*)A)[d4];
    const f4 bb = ((const f4*)B)[d4];
    const f4 cc = ((const f4*)Cv)[d4];
    const f4 dd = ((const f4*)Dv)[d4];
    const f4 a2 = fin4(a * a), a4 = fin4(a2 * a2), a8 = fin4(a4 * a4);
    const f4 ONE = {1.f, 1.f, 1.f, 1.f};
    const f4 ZERO = {0.f, 0.f, 0.f, 0.f};

    f4 S = ZERO;  // tile-running state, maintained redundantly in ALL threads

    // My row pointer: row (t*TTILE + sub*TSUB + i), channel ch.
    const size_t slice = (size_t)b * TLEN * D4 + (size_t)dg * DG + ch;
    const f4* xp = (const f4*)xg + slice + (size_t)sub * TSUB * D4;
    f4* yp = (f4*)yg + slice + (size_t)sub * TSUB * D4;

    // ---- Prologue: load tile 0 directly into registers. ----
    f4 xcur[TSUB], xnext[TSUB];
#pragma unroll
    for (int i = 0; i < TSUB; ++i) xcur[i] = xp[(size_t)i * D4];

    for (int t = 0; t < NTILE; ++t) {
        const int pb = t & 1;

        // (A) issue next tile's loads NOW; consumed at the rotate below.
        // They fly under the scan + barriers (HBM latency hidden).
        if (t + 1 < NTILE) {
            const f4* xn = xp + (size_t)(t + 1) * TTILE * D4;
#pragma unroll
            for (int i = 0; i < TSUB; ++i) xnext[i] = xn[(size_t)i * D4];
        }

        // (B) local scan of my 8 rows -> my subchunk's affine map (a8, v).
        pr me;
        {
            f4 v = ZERO;
#pragma unroll
            for (int i = 0; i < TSUB; ++i) v = fin4(a * v + bb * xcur[i]);
            me.p = a8; me.v = v;
        }

        // (B2) in-wave Kogge-Stone inclusive scan over the 8 subs (shuffles).
#pragma unroll
        for (int d = 1; d <= 4; d <<= 1) {
            pr up;
            up.p = shflup4(me.p, 8 * d);
            up.v = shflup4(me.v, 8 * d);
            if (siw >= d) me = comp(me, up);
        }
        if (siw == 7) { wpP[pb][wid * DG + ch] = me.p; wpV[pb][wid * DG + ch] = me.v; }
        BAR();

        // (B3) wave 0 scans the 8 wave-partials per channel; writes exclusive
        // prefixes back and the tile-total pair.
        if (tid < 64) {
            const int ww = tid >> 3, c2 = tid & 7;
            pr q; q.p = wpP[pb][tid]; q.v = wpV[pb][tid];
#pragma unroll
            for (int d = 1; d <= 4; d <<= 1) {
                pr up;
                up.p = shflup4(q.p, 8 * d);
                up.v = shflup4(q.v, 8 * d);
                if (ww >= d) q = comp(q, up);
            }
            if (ww == 7) { totP[pb][c2] = q.p; totV[pb][c2] = q.v; }
            pr ex;
            ex.p = shflup4(q.p, 8);
            ex.v = shflup4(q.v, 8);
            if (ww == 0) { ex.p = ONE; ex.v = ZERO; }
            wpP[pb][tid] = ex.p; wpV[pb][tid] = ex.v;
        }
        BAR();

        // (B4) my exclusive start state = (within-wave excl) ∘ (wave excl),
        // applied to the running state S.
        pr wex; wex.p = wpP[pb][wid * DG + ch]; wex.v = wpV[pb][wid * DG + ch];
        pr mex;
        mex.p = shflup4(me.p, 8);
        mex.v = shflup4(me.v, 8);
        if (siw == 0) { mex.p = ONE; mex.v = ZERO; }
        pr st = comp(mex, wex);
        f4 s = fin4(fin4(st.p * S) + st.v);

        // advance S by the tile total (all threads, consistent per channel).
        S = fin4(fin4(totP[pb][ch] * S) + totV[pb][ch]);

        // (E) rescan my rows from s; store y DIRECTLY from registers
        // (8 same-sub lanes x 16B = 128B contiguous per row), non-temporal.
        f4* yt = yp + (size_t)t * TTILE * D4;
#pragma unroll
        for (int i = 0; i < TSUB; ++i) {
            f4 xi = xcur[i];
            s = fin4(a * s + bb * xi);
            f4 yv = fin4(cc * s + dd * xi);
            __builtin_nontemporal_store(yv, yt + (size_t)i * D4);
        }

        // rotate prefetched tile into xcur (reg-reg; compiler places the
        // precise vmcnt wait for xnext here).
        if (t + 1 < NTILE) {
#pragma unroll
            for (int i = 0; i < TSUB; ++i) xcur[i] = xnext[i];
        }
    }
}

extern "C" void kernel_launch(void* const* d_in, const int* in_sizes, int n_in,
                              void* d_out, int out_size, void* d_ws, size_t ws_size,
                              hipStream_t stream) {
    const float* x  = (const float*)d_in[0];
    const float* A  = (const float*)d_in[1];
    const float* B  = (const float*)d_in[2];
    const float* Cv = (const float*)d_in[3];
    const float* Dv = (const float*)d_in[4];
    float* y = (float*)d_out;

    const int nblocks = BATCHN * NDG;  // 256 blocks x 512 threads, 1 block/CU
    ssm_direct<<<nblocks, THREADS, 0, stream>>>(x, A, B, Cv, Dv, y);
}